// Round 17
// baseline (336.521 us; speedup 1.0000x reference)
//
#include <hip/hip_runtime.h>
#include <hip/hip_bf16.h>

#define BATCH 262144
#define DIN 48
#define HDIM 256
#define DOUT 12
#define EPSV 1e-5f

// R17: NO LDS, NO BARRIERS. 256 threads (4 waves); each wave owns 32 batch
// rows (2 r-tiles), fully independent. Weights (300 KB, frag-major, phi
// k-order) are L1/L2-resident; A-frags read DIRECTLY from global: per-wave
// 1KB coalesced reads, identical across the block's waves (L1 broadcast).
// Waves free-run -> MFMA/VALU/VMEM phases of different waves overlap without
// any lockstep. Compiler manages all waits (no hand vmcnt -> no entanglement).
#define ROWS_PER_BLOCK 128
#define NBLK (BATCH / ROWS_PER_BLOCK)

typedef __attribute__((ext_vector_type(4))) float f32x4;
typedef __attribute__((ext_vector_type(2))) float f32x2;
typedef __attribute__((ext_vector_type(8))) short bf16x8;

union FragU { bf16x8 v; unsigned u[4]; };

// ws layout (ushort), FRAGMENT-MAJOR:
//   idx-in-region = ((s*16 + t)*64 + lane)*8 + j
//   W1 region: k = 32s + 8*(lane>>4) + j          (linear)
//   W2/W3/Wm:  k = phi(s, lane>>4, j)             (permuted)
#define W1F_OFF 0          // 2 slabs  (K=64: k<48 -> W1, k==48 -> b1, else 0)
#define W2F_OFF 16384      // 8 slabs
#define W3F_OFF 81920      // 8 slabs
#define WMF_OFF 147456     // 4096
#define WS_ELEMS 151552

__device__ __forceinline__ unsigned short f2b(float f) {
    union { float f; unsigned u; } v; v.f = f;
    unsigned r = (v.u + 0x7fffu + ((v.u >> 16) & 1u)) >> 16;  // RNE
    return (unsigned short)r;
}

__device__ __forceinline__ unsigned packbf(float a, float b) {
    float2 t; t.x = a; t.y = b;
    __hip_bfloat162 h = __float22bfloat162_rn(t);
    union { __hip_bfloat162 h; unsigned u; } c; c.h = h;
    return c.u;
}

__device__ __forceinline__ float fast_tanh(float x) {
    const float t = __expf(2.0f * x);
    return fmaf(-2.0f, __builtin_amdgcn_rcpf(t + 1.0f), 1.0f);
}

__global__ void conv_w_kernel(const float* __restrict__ W1, const float* __restrict__ b1,
                              const float* __restrict__ W2, const float* __restrict__ W3,
                              const float* __restrict__ Wm,
                              unsigned short* __restrict__ ws) {
    int i = blockIdx.x * 256 + threadIdx.x;
    if (i >= WS_ELEMS) return;
    float v;
    if (i < W2F_OFF) {
        const int j = i & 7, l = (i >> 3) & 63, t = (i >> 9) & 15, s = i >> 13;
        const int n = 16 * t + (l & 15), k = 32 * s + 8 * (l >> 4) + j;  // linear
        v = (k < DIN) ? W1[k * HDIM + n] : (k == DIN ? b1[n] : 0.0f);
    } else if (i < W3F_OFF) {
        const int i2 = i - W2F_OFF;
        const int j = i2 & 7, l = (i2 >> 3) & 63, t = (i2 >> 9) & 15, s = i2 >> 13;
        const int n = 16 * t + (l & 15);
        const int k = 32 * s + ((j >= 4) ? 16 : 0) + 4 * (l >> 4) + (j & 3);  // phi
        v = W2[k * HDIM + n];
    } else if (i < WMF_OFF) {
        const int i3 = i - W3F_OFF;
        const int j = i3 & 7, l = (i3 >> 3) & 63, t = (i3 >> 9) & 15, s = i3 >> 13;
        const int n = 16 * t + (l & 15);
        const int k = 32 * s + ((j >= 4) ? 16 : 0) + 4 * (l >> 4) + (j & 3);  // phi
        v = W3[k * HDIM + n];
    } else {
        const int i4 = i - WMF_OFF;
        const int j = i4 & 7, l = (i4 >> 3) & 63, ks = i4 >> 9;
        const int n = l & 15;
        const int k = 32 * ks + ((j >= 4) ? 16 : 0) + 4 * (l >> 4) + (j & 3); // phi
        v = (n < DOUT) ? Wm[k * DOUT + n] : 0.0f;
    }
    ws[i] = f2b(v);
}

// one full layer (KS slabs of 32-k): A-frags straight from global (L1/L2).
// acc[rt][t] accumulates over s. Compiler software-pipelines the loads.
template<int KS>
__device__ __forceinline__ void mm_layer_g(
    f32x4 (&acc)[2][16], const FragU (&bf)[2][8],
    const unsigned short* __restrict__ wf, int lane)
{
    #pragma unroll
    for (int s = 0; s < KS; s++) {
        #pragma unroll
        for (int t = 0; t < 16; t++) {
            const bf16x8 A = *(const bf16x8*)&wf[((s * 16 + t) * 64 + lane) * 8];
            acc[0][t] = __builtin_amdgcn_mfma_f32_16x16x32_bf16(A, bf[0][s].v, acc[0][t], 0, 0, 0);
            acc[1][t] = __builtin_amdgcn_mfma_f32_16x16x32_bf16(A, bf[1][s].v, acc[1][t], 0, 0, 0);
        }
    }
}

#define SV2(v, a, b) __builtin_shufflevector(v, v, a, b)

// LayerNorm + ReLU + bf16 pack, packed-f32. Bias already in acc. B-frags
// lane-local thanks to phi. gamma/beta straight from global (L1 hits,
// compiler-managed waits).
__device__ __forceinline__ void build_frags(
    const f32x4 (&acc)[2][16], FragU (&bfo)[2][8],
    const float* __restrict__ gt, const float* __restrict__ bt, int lane)
{
    const int q4 = (lane >> 4) * 4;
    #pragma unroll
    for (int rt = 0; rt < 2; rt++) {
        f32x2 s2 = {0.f, 0.f}, p2 = {0.f, 0.f};
        #pragma unroll
        for (int t = 0; t < 16; t++) {
            const f32x2 a = SV2(acc[rt][t], 0, 1);
            const f32x2 b = SV2(acc[rt][t], 2, 3);
            s2 += a; s2 += b;
            p2 += a * a; p2 += b * b;
        }
        float ss = s2[0] + s2[1];
        float qq = p2[0] + p2[1];
        ss += __shfl_xor(ss, 16); ss += __shfl_xor(ss, 32);
        qq += __shfl_xor(qq, 16); qq += __shfl_xor(qq, 32);
        const float mu = ss * (1.0f / 256.0f);
        const float rs = __builtin_amdgcn_rsqf(
            fmaxf(qq * (1.0f / 256.0f) - mu * mu, 0.0f) + EPSV);
        const float nb = -mu * rs;
        const f32x2 rs2 = {rs, rs}, nb2 = {nb, nb}, z2 = {0.f, 0.f};
        #pragma unroll
        for (int ks = 0; ks < 8; ks++) {
            const f32x4 g0 = *(const f32x4*)&gt[32 * ks + q4];
            const f32x4 e0 = *(const f32x4*)&bt[32 * ks + q4];
            const f32x4 g1 = *(const f32x4*)&gt[32 * ks + 16 + q4];
            const f32x4 e1 = *(const f32x4*)&bt[32 * ks + 16 + q4];
            const f32x2 v00 = SV2(acc[rt][2 * ks], 0, 1);
            const f32x2 v01 = SV2(acc[rt][2 * ks], 2, 3);
            const f32x2 v10 = SV2(acc[rt][2 * ks + 1], 0, 1);
            const f32x2 v11 = SV2(acc[rt][2 * ks + 1], 2, 3);
            const f32x2 w00 = __builtin_elementwise_max(
                (v00 * rs2 + nb2) * SV2(g0, 0, 1) + SV2(e0, 0, 1), z2);
            const f32x2 w01 = __builtin_elementwise_max(
                (v01 * rs2 + nb2) * SV2(g0, 2, 3) + SV2(e0, 2, 3), z2);
            const f32x2 w10 = __builtin_elementwise_max(
                (v10 * rs2 + nb2) * SV2(g1, 0, 1) + SV2(e1, 0, 1), z2);
            const f32x2 w11 = __builtin_elementwise_max(
                (v11 * rs2 + nb2) * SV2(g1, 2, 3) + SV2(e1, 2, 3), z2);
            bfo[rt][ks].u[0] = packbf(w00[0], w00[1]);
            bfo[rt][ks].u[1] = packbf(w01[0], w01[1]);
            bfo[rt][ks].u[2] = packbf(w10[0], w10[1]);
            bfo[rt][ks].u[3] = packbf(w11[0], w11[1]);
        }
    }
}

__device__ __forceinline__ void zero_acc(f32x4 (&acc)[2][16]) {
    #pragma unroll
    for (int rt = 0; rt < 2; rt++)
        #pragma unroll
        for (int t = 0; t < 16; t++)
            acc[rt][t] = (f32x4){0.f, 0.f, 0.f, 0.f};
}

// bias (from global, L1-served) into accumulator init
__device__ __forceinline__ void init_acc_bias(f32x4 (&acc)[2][16],
                                              const float* __restrict__ bt, int q) {
    #pragma unroll
    for (int t = 0; t < 16; t++) {
        const f32x4 b = *(const f32x4*)&bt[16 * t + 4 * q];
        acc[0][t] = b;
        acc[1][t] = b;
    }
}

__global__ __launch_bounds__(256, 2) void fused_mlp(
    const float* __restrict__ x,
    const float* __restrict__ g1, const float* __restrict__ be1,
    const float* __restrict__ b2, const float* __restrict__ g2, const float* __restrict__ be2,
    const float* __restrict__ b3, const float* __restrict__ g3, const float* __restrict__ be3,
    const float* __restrict__ bm,
    const unsigned short* __restrict__ ws,
    float* __restrict__ out)
{
    const int tid = threadIdx.x;
    const int wv = tid >> 6, lane = tid & 63;
    const int l15 = lane & 15, q = lane >> 4;
    const int wrow0 = blockIdx.x * ROWS_PER_BLOCK + wv * 32;

    const unsigned short* w1f = ws + W1F_OFF;
    const unsigned short* w2f = ws + W2F_OFF;
    const unsigned short* w3f = ws + W3F_OFF;
    const unsigned short* wmf = ws + WMF_OFF;

    // ---- x -> layer-1 B-frags (transposed bf16), bias = k=48 ones-row ----
    FragU bf[2][8];
    #pragma unroll
    for (int rt = 0; rt < 2; rt++) {
        const float* xr = x + (size_t)(wrow0 + rt * 16 + l15) * DIN;
        const float4 f0 = *(const float4*)(xr + q * 8);
        const float4 f1 = *(const float4*)(xr + q * 8 + 4);
        bf[rt][0].u[0] = packbf(f0.x, f0.y); bf[rt][0].u[1] = packbf(f0.z, f0.w);
        bf[rt][0].u[2] = packbf(f1.x, f1.y); bf[rt][0].u[3] = packbf(f1.z, f1.w);
        if (q < 2) {
            const float4 f2 = *(const float4*)(xr + 32 + q * 8);
            const float4 f3 = *(const float4*)(xr + 36 + q * 8);
            bf[rt][1].u[0] = packbf(f2.x, f2.y); bf[rt][1].u[1] = packbf(f2.z, f2.w);
            bf[rt][1].u[2] = packbf(f3.x, f3.y); bf[rt][1].u[3] = packbf(f3.z, f3.w);
        } else if (q == 2) {
            bf[rt][1].u[0] = 0x00003F80u;  // k=48 -> 1.0 (bias row)
            bf[rt][1].u[1] = 0u; bf[rt][1].u[2] = 0u; bf[rt][1].u[3] = 0u;
        } else {
            bf[rt][1].u[0] = 0u; bf[rt][1].u[1] = 0u;
            bf[rt][1].u[2] = 0u; bf[rt][1].u[3] = 0u;
        }
    }

    f32x4 acc[2][16];

    // ---- layer 1 (K=64, linear k-order) ----
    zero_acc(acc);                       // layer-1 bias is the k=48 ones-row
    mm_layer_g<2>(acc, bf, w1f, lane);
    build_frags(acc, bf, g1, be1, lane);

    // ---- layer 2 (K=256, phi k-order) ----
    init_acc_bias(acc, b2, q);
    mm_layer_g<8>(acc, bf, w2f, lane);
    build_frags(acc, bf, g2, be2, lane);

    // ---- layer 3 (K=256, phi k-order) ----
    init_acc_bias(acc, b3, q);
    mm_layer_g<8>(acc, bf, w3f, lane);
    build_frags(acc, bf, g3, be3, lane);

    // ---- final layer: Wm (8 KB, L1-resident) ----
    f32x4 facc[2];
    {
        f32x4 bm4 = {0.f, 0.f, 0.f, 0.f};
        if (q < 3) bm4 = *(const f32x4*)&bm[4 * q];
        facc[0] = bm4;
        facc[1] = bm4;
    }
    #pragma unroll
    for (int ks = 0; ks < 8; ks++) {
        const bf16x8 A = *(const bf16x8*)&wmf[(ks * 64 + lane) * 8];
        facc[0] = __builtin_amdgcn_mfma_f32_16x16x32_bf16(A, bf[0][ks].v, facc[0], 0, 0, 0);
        facc[1] = __builtin_amdgcn_mfma_f32_16x16x32_bf16(A, bf[1][ks].v, facc[1], 0, 0, 0);
    }
    // ---- direct coalesced stores: feature = 4q+j, row = rt*16+l15 ----
    if (q < 3) {
        #pragma unroll
        for (int rt = 0; rt < 2; rt++) {
            float4 o;
            o.x = fast_tanh(facc[rt][0]);
            o.y = fast_tanh(facc[rt][1]);
            o.z = fast_tanh(facc[rt][2]);
            o.w = fast_tanh(facc[rt][3]);
            *(float4*)&out[(size_t)(wrow0 + rt * 16 + l15) * DOUT + q * 4] = o;
        }
    }
}

extern "C" void kernel_launch(void* const* d_in, const int* in_sizes, int n_in,
                              void* d_out, int out_size, void* d_ws, size_t ws_size,
                              hipStream_t stream)
{
    const float* x   = (const float*)d_in[0];
    const float* W1  = (const float*)d_in[1];
    const float* b1  = (const float*)d_in[2];
    const float* g1  = (const float*)d_in[3];
    const float* be1 = (const float*)d_in[4];
    const float* W2  = (const float*)d_in[5];
    const float* b2  = (const float*)d_in[6];
    const float* g2  = (const float*)d_in[7];
    const float* be2 = (const float*)d_in[8];
    const float* W3  = (const float*)d_in[9];
    const float* b3  = (const float*)d_in[10];
    const float* g3  = (const float*)d_in[11];
    const float* be3 = (const float*)d_in[12];
    const float* Wm  = (const float*)d_in[13];
    const float* bm  = (const float*)d_in[14];
    unsigned short* ws = (unsigned short*)d_ws;
    float* out = (float*)d_out;

    conv_w_kernel<<<(WS_ELEMS + 255) / 256, 256, 0, stream>>>(W1, b1, W2, W3, Wm, ws);
    fused_mlp<<<NBLK, 256, 0, stream>>>(x, g1, be1, b2, g2, be2,
                                        b3, g3, be3, bm, ws, out);
}

// Round 18
// 100.601 us; speedup vs baseline: 3.3451x; 3.3451x over previous
//
#include <hip/hip_runtime.h>
#include <hip/hip_bf16.h>

#define BATCH 262144
#define DIN 48
#define HDIM 256
#define DOUT 12
#define EPSV 1e-5f

// R18 = R11 restored (best measured: 100.5 us).
// 256 threads (4 waves); each wave owns 32 batch rows (2 r-tiles of 16).
// Activations TRANSPOSED in registers. Weights for layers 2/3/final use
// PERMUTED k-order phi so next-layer B-frags are lane-local.
// Slab-granular (16KB) quad-buffered staging with counted
// s_waitcnt vmcnt(8) + raw s_barrier -> staging loads never drain,
// packed-f32 (v_pk_*) LayerNorm math.
#define ROWS_PER_BLOCK 128
#define NBLK (BATCH / ROWS_PER_BLOCK)

typedef __attribute__((ext_vector_type(4))) float f32x4;
typedef __attribute__((ext_vector_type(2))) float f32x2;
typedef __attribute__((ext_vector_type(8))) short bf16x8;

union FragU { bf16x8 v; unsigned u[4]; };

// ws layout (ushort), FRAGMENT-MAJOR:
//   idx-in-region = ((s*16 + t)*64 + lane)*8 + j
//   W1 region: k = 32s + 8*(lane>>4) + j          (linear)
//   W2/W3/Wm:  k = phi(s, lane>>4, j)             (permuted)
#define W1F_OFF 0          // 2 slabs  (K=64: k<48 -> W1, k==48 -> b1, else 0)
#define W2F_OFF 16384      // 8 slabs
#define W3F_OFF 81920      // 8 slabs
#define WMF_OFF 147456     // 4096
#define WS_ELEMS 151552

#define WAITV(n) asm volatile("s_waitcnt vmcnt(" #n ")" ::: "memory")

__device__ __forceinline__ unsigned short f2b(float f) {
    union { float f; unsigned u; } v; v.f = f;
    unsigned r = (v.u + 0x7fffu + ((v.u >> 16) & 1u)) >> 16;  // RNE
    return (unsigned short)r;
}

__device__ __forceinline__ unsigned packbf(float a, float b) {
    float2 t; t.x = a; t.y = b;
    __hip_bfloat162 h = __float22bfloat162_rn(t);
    union { __hip_bfloat162 h; unsigned u; } c; c.h = h;
    return c.u;
}

__device__ __forceinline__ float fast_tanh(float x) {
    const float t = __expf(2.0f * x);
    return fmaf(-2.0f, __builtin_amdgcn_rcpf(t + 1.0f), 1.0f);
}

__global__ void conv_w_kernel(const float* __restrict__ W1, const float* __restrict__ b1,
                              const float* __restrict__ W2, const float* __restrict__ W3,
                              const float* __restrict__ Wm,
                              unsigned short* __restrict__ ws) {
    int i = blockIdx.x * 256 + threadIdx.x;
    if (i >= WS_ELEMS) return;
    float v;
    if (i < W2F_OFF) {
        const int j = i & 7, l = (i >> 3) & 63, t = (i >> 9) & 15, s = i >> 13;
        const int n = 16 * t + (l & 15), k = 32 * s + 8 * (l >> 4) + j;  // linear
        v = (k < DIN) ? W1[k * HDIM + n] : (k == DIN ? b1[n] : 0.0f);
    } else if (i < W3F_OFF) {
        const int i2 = i - W2F_OFF;
        const int j = i2 & 7, l = (i2 >> 3) & 63, t = (i2 >> 9) & 15, s = i2 >> 13;
        const int n = 16 * t + (l & 15);
        const int k = 32 * s + ((j >= 4) ? 16 : 0) + 4 * (l >> 4) + (j & 3);  // phi
        v = W2[k * HDIM + n];
    } else if (i < WMF_OFF) {
        const int i3 = i - W3F_OFF;
        const int j = i3 & 7, l = (i3 >> 3) & 63, t = (i3 >> 9) & 15, s = i3 >> 13;
        const int n = 16 * t + (l & 15);
        const int k = 32 * s + ((j >= 4) ? 16 : 0) + 4 * (l >> 4) + (j & 3);  // phi
        v = W3[k * HDIM + n];
    } else {
        const int i4 = i - WMF_OFF;
        const int j = i4 & 7, l = (i4 >> 3) & 63, ks = i4 >> 9;
        const int n = l & 15;
        const int k = 32 * ks + ((j >= 4) ? 16 : 0) + 4 * (l >> 4) + (j & 3); // phi
        v = (n < DOUT) ? Wm[k * DOUT + n] : 0.0f;
    }
    ws[i] = f2b(v);
}

// async 16B global->LDS copy (HW DMA; dest = base + lane*16)
__device__ __forceinline__ void gll16(const void* g, void* l) {
    __builtin_amdgcn_global_load_lds(
        (const __attribute__((address_space(1))) unsigned int*)g,
        (__attribute__((address_space(3))) unsigned int*)l, 16, 0, 0);
}

// stage one 16KB slab: 4 chunks of 4KB, lane-contiguous (4 vmcnt events)
__device__ __forceinline__ void stage_slab(const unsigned short* __restrict__ src,
                                           unsigned short* dst, int tid) {
    const char* g = (const char*)src + tid * 16;
    char* l = (char*)dst + tid * 16;
    #pragma unroll
    for (int c = 0; c < 4; c++)
        gll16(g + c * 4096, l + c * 4096);
}

// one 32-k slab of MFMAs: A-frag(t) = sb + t*1KB + lane*16B, conflict-free;
// each A-read feeds both r-tiles.
__device__ __forceinline__ void compute_slab(
    f32x4 (&acc)[2][16], const FragU& b0, const FragU& b1,
    const unsigned short* sb, int lane)
{
    __builtin_amdgcn_s_setprio(1);
    #pragma unroll
    for (int t = 0; t < 16; t++) {
        const bf16x8 A = *(const bf16x8*)&sb[(t * 64 + lane) * 8];
        acc[0][t] = __builtin_amdgcn_mfma_f32_16x16x32_bf16(A, b0.v, acc[0][t], 0, 0, 0);
        acc[1][t] = __builtin_amdgcn_mfma_f32_16x16x32_bf16(A, b1.v, acc[1][t], 0, 0, 0);
    }
    __builtin_amdgcn_s_setprio(0);
}

#define SV2(v, a, b) __builtin_shufflevector(v, v, a, b)

// LayerNorm + ReLU + bf16 pack, packed-f32 (f32x2 -> v_pk_*). Bias already
// in acc. B-frags lane-local thanks to phi:
//   u[0..1] <- features 32ks+4q+{0..3}    (t = 2ks)
//   u[2..3] <- features 32ks+16+4q+{0..3} (t = 2ks+1)
__device__ __forceinline__ void build_frags(
    const f32x4 (&acc)[2][16], FragU (&bfo)[2][8],
    const float* __restrict__ gt, const float* __restrict__ bt, int lane)
{
    const int q4 = (lane >> 4) * 4;
    #pragma unroll
    for (int rt = 0; rt < 2; rt++) {
        f32x2 s2 = {0.f, 0.f}, p2 = {0.f, 0.f};
        #pragma unroll
        for (int t = 0; t < 16; t++) {
            const f32x2 a = SV2(acc[rt][t], 0, 1);
            const f32x2 b = SV2(acc[rt][t], 2, 3);
            s2 += a; s2 += b;
            p2 += a * a; p2 += b * b;
        }
        float ss = s2[0] + s2[1];
        float qq = p2[0] + p2[1];
        ss += __shfl_xor(ss, 16); ss += __shfl_xor(ss, 32);
        qq += __shfl_xor(qq, 16); qq += __shfl_xor(qq, 32);
        const float mu = ss * (1.0f / 256.0f);
        const float rs = __builtin_amdgcn_rsqf(
            fmaxf(qq * (1.0f / 256.0f) - mu * mu, 0.0f) + EPSV);
        const float nb = -mu * rs;
        const f32x2 rs2 = {rs, rs}, nb2 = {nb, nb}, z2 = {0.f, 0.f};
        #pragma unroll
        for (int ks = 0; ks < 8; ks++) {
            const f32x4 g0 = *(const f32x4*)&gt[32 * ks + q4];
            const f32x4 e0 = *(const f32x4*)&bt[32 * ks + q4];
            const f32x4 g1 = *(const f32x4*)&gt[32 * ks + 16 + q4];
            const f32x4 e1 = *(const f32x4*)&bt[32 * ks + 16 + q4];
            const f32x2 v00 = SV2(acc[rt][2 * ks], 0, 1);
            const f32x2 v01 = SV2(acc[rt][2 * ks], 2, 3);
            const f32x2 v10 = SV2(acc[rt][2 * ks + 1], 0, 1);
            const f32x2 v11 = SV2(acc[rt][2 * ks + 1], 2, 3);
            const f32x2 w00 = __builtin_elementwise_max(
                (v00 * rs2 + nb2) * SV2(g0, 0, 1) + SV2(e0, 0, 1), z2);
            const f32x2 w01 = __builtin_elementwise_max(
                (v01 * rs2 + nb2) * SV2(g0, 2, 3) + SV2(e0, 2, 3), z2);
            const f32x2 w10 = __builtin_elementwise_max(
                (v10 * rs2 + nb2) * SV2(g1, 0, 1) + SV2(e1, 0, 1), z2);
            const f32x2 w11 = __builtin_elementwise_max(
                (v11 * rs2 + nb2) * SV2(g1, 2, 3) + SV2(e1, 2, 3), z2);
            bfo[rt][ks].u[0] = packbf(w00[0], w00[1]);
            bfo[rt][ks].u[1] = packbf(w01[0], w01[1]);
            bfo[rt][ks].u[2] = packbf(w10[0], w10[1]);
            bfo[rt][ks].u[3] = packbf(w11[0], w11[1]);
        }
    }
}

__device__ __forceinline__ void zero_acc(f32x4 (&acc)[2][16]) {
    #pragma unroll
    for (int rt = 0; rt < 2; rt++)
        #pragma unroll
        for (int t = 0; t < 16; t++)
            acc[rt][t] = (f32x4){0.f, 0.f, 0.f, 0.f};
}

__device__ __forceinline__ void init_acc_bias(f32x4 (&acc)[2][16],
                                              const float* __restrict__ bt, int q) {
    #pragma unroll
    for (int t = 0; t < 16; t++) {
        const f32x4 b = *(const f32x4*)&bt[16 * t + 4 * q];
        acc[0][t] = b;
        acc[1][t] = b;
    }
}

__global__ __launch_bounds__(256, 2) void fused_mlp(
    const float* __restrict__ x,
    const float* __restrict__ g1, const float* __restrict__ be1,
    const float* __restrict__ b2, const float* __restrict__ g2, const float* __restrict__ be2,
    const float* __restrict__ b3, const float* __restrict__ g3, const float* __restrict__ be3,
    const float* __restrict__ bm,
    const unsigned short* __restrict__ ws,
    float* __restrict__ out)
{
    __shared__ unsigned short buf[4][8192];    // 64 KB: quad-buffered 16KB slabs
    __shared__ float gtab[3][256];             // 3 KB gamma
    __shared__ float betab[3][256];            // 3 KB beta
    __shared__ float btab[2][256];             // 2 KB b2,b3
    __shared__ float bmt[16];
    __shared__ float ostage[4][384];           // 6 KB -> ~78 KB total (2 blk/CU)

    const int tid = threadIdx.x;
    const int wv = tid >> 6, lane = tid & 63;
    const int l15 = lane & 15, q = lane >> 4;
    const int wrow0 = blockIdx.x * ROWS_PER_BLOCK + wv * 32;

    const unsigned short* w1f = ws + W1F_OFF;
    const unsigned short* w2f = ws + W2F_OFF;
    const unsigned short* w3f = ws + W3F_OFF;
    const unsigned short* wmf = ws + WMF_OFF;

    // ---- prologue: stage W1 slabs 0,1 (8 loads in flight) ----
    stage_slab(w1f, &buf[0][0], tid);
    stage_slab(w1f + 8192, &buf[1][0], tid);

    // ---- tables -> LDS ----
    {
        const int n = tid;
        gtab[0][n] = g1[n];  betab[0][n] = be1[n];
        gtab[1][n] = g2[n];  betab[1][n] = be2[n];
        gtab[2][n] = g3[n];  betab[2][n] = be3[n];
        btab[0][n] = b2[n];
        btab[1][n] = b3[n];
        if (tid < 16) bmt[tid] = (tid < DOUT) ? bm[tid] : 0.f;
    }
    // ---- x -> layer-1 B-frags (into bf[rt][0..1]), bias = k=48 ones-row ----
    FragU bf[2][8];
    #pragma unroll
    for (int rt = 0; rt < 2; rt++) {
        const float* xr = x + (size_t)(wrow0 + rt * 16 + l15) * DIN;
        const float4 f0 = *(const float4*)(xr + q * 8);
        const float4 f1 = *(const float4*)(xr + q * 8 + 4);
        bf[rt][0].u[0] = packbf(f0.x, f0.y); bf[rt][0].u[1] = packbf(f0.z, f0.w);
        bf[rt][0].u[2] = packbf(f1.x, f1.y); bf[rt][0].u[3] = packbf(f1.z, f1.w);
        if (q < 2) {
            const float4 f2 = *(const float4*)(xr + 32 + q * 8);
            const float4 f3 = *(const float4*)(xr + 36 + q * 8);
            bf[rt][1].u[0] = packbf(f2.x, f2.y); bf[rt][1].u[1] = packbf(f2.z, f2.w);
            bf[rt][1].u[2] = packbf(f3.x, f3.y); bf[rt][1].u[3] = packbf(f3.z, f3.w);
        } else if (q == 2) {
            bf[rt][1].u[0] = 0x00003F80u;  // k=48 -> 1.0 (bias row)
            bf[rt][1].u[1] = 0u; bf[rt][1].u[2] = 0u; bf[rt][1].u[3] = 0u;
        } else {
            bf[rt][1].u[0] = 0u; bf[rt][1].u[1] = 0u;
            bf[rt][1].u[2] = 0u; bf[rt][1].u[3] = 0u;
        }
    }
    // one-time fence: table ds_writes visible before first raw barrier
    asm volatile("s_waitcnt lgkmcnt(0)" ::: "memory");

    f32x4 acc[2][16];

    // ================= pipelined 18-slab main loop =================
    // step sigma: stage(sigma+2) -> vmcnt(8) -> s_barrier -> compute(sigma)
    // quad-buffer ring: writer sigma+2 vs readers sigma-2 (distance 4, safe).

    // ---- layer 1: sigma = 0,1 ----
    zero_acc(acc);                       // layer-1 bias is the k=48 ones-row
    #pragma unroll
    for (int s = 0; s < 2; s++) {
        stage_slab(w2f + s * 8192, &buf[(s + 2) & 3][0], tid);
        WAITV(8);
        __builtin_amdgcn_s_barrier();
        __builtin_amdgcn_sched_barrier(0);
        compute_slab(acc, bf[0][s], bf[1][s], &buf[s][0], lane);
    }
    build_frags(acc, bf, &gtab[0][0], &betab[0][0], lane);

    // ---- layer 2: sigma = 2..9 ----
    init_acc_bias(acc, &btab[0][0], q);  // b2
    #pragma unroll
    for (int s = 0; s < 8; s++) {
        const unsigned short* nsrc = (s < 6) ? (w2f + (s + 2) * 8192)
                                             : (w3f + (s - 6) * 8192);
        stage_slab(nsrc, &buf[(s + 4) & 3][0], tid);
        WAITV(8);
        __builtin_amdgcn_s_barrier();
        __builtin_amdgcn_sched_barrier(0);
        compute_slab(acc, bf[0][s], bf[1][s], &buf[(s + 2) & 3][0], lane);
    }
    build_frags(acc, bf, &gtab[1][0], &betab[1][0], lane);

    // ---- layer 3: sigma = 10..17 ----
    init_acc_bias(acc, &btab[1][0], q);  // b3
    #pragma unroll
    for (int s = 0; s < 8; s++) {
        if (s < 6) stage_slab(w3f + (s + 2) * 8192, &buf[(s + 12) & 3][0], tid);
        if (s < 6)      { WAITV(8); }
        else if (s == 6){ WAITV(4); }
        else            { WAITV(0); }
        __builtin_amdgcn_s_barrier();
        __builtin_amdgcn_sched_barrier(0);
        compute_slab(acc, bf[0][s], bf[1][s], &buf[(s + 10) & 3][0], lane);
    }
    build_frags(acc, bf, &gtab[2][0], &betab[2][0], lane);

    // ---- final layer: Wm frag-major (phi k-order) from global (L2-resident) ----
    f32x4 facc[2];
    {
        const f32x4 bm4 = *(const f32x4*)&bmt[4 * q];
        facc[0] = bm4;
        facc[1] = bm4;
    }
    #pragma unroll
    for (int ks = 0; ks < 8; ks++) {
        const bf16x8 A = *(const bf16x8*)&wmf[(ks * 64 + lane) * 8];
        facc[0] = __builtin_amdgcn_mfma_f32_16x16x32_bf16(A, bf[0][ks].v, facc[0], 0, 0, 0);
        facc[1] = __builtin_amdgcn_mfma_f32_16x16x32_bf16(A, bf[1][ks].v, facc[1], 0, 0, 0);
    }
    // tanh -> wave-private LDS staging (row = rt*16+l15, cols 4q..4q+3 for q<3)
    if (q < 3) {
        #pragma unroll
        for (int rt = 0; rt < 2; rt++) {
            float4 o;
            o.x = fast_tanh(facc[rt][0]);
            o.y = fast_tanh(facc[rt][1]);
            o.z = fast_tanh(facc[rt][2]);
            o.w = fast_tanh(facc[rt][3]);
            *(float4*)&ostage[wv][(rt * 16 + l15) * 12 + q * 4] = o;
        }
    }
    // coalesced store: 32 rows x 12 f32 = 96 float4 per wave (same-wave LDS,
    // compiler handles lgkm ordering; no block barrier needed)
    float4* og = (float4*)(out + (size_t)wrow0 * DOUT);
    const float4* ov = (const float4*)&ostage[wv][0];
    og[lane] = ov[lane];
    if (lane < 32) og[64 + lane] = ov[64 + lane];
}

extern "C" void kernel_launch(void* const* d_in, const int* in_sizes, int n_in,
                              void* d_out, int out_size, void* d_ws, size_t ws_size,
                              hipStream_t stream)
{
    const float* x   = (const float*)d_in[0];
    const float* W1  = (const float*)d_in[1];
    const float* b1  = (const float*)d_in[2];
    const float* g1  = (const float*)d_in[3];
    const float* be1 = (const float*)d_in[4];
    const float* W2  = (const float*)d_in[5];
    const float* b2  = (const float*)d_in[6];
    const float* g2  = (const float*)d_in[7];
    const float* be2 = (const float*)d_in[8];
    const float* W3  = (const float*)d_in[9];
    const float* b3  = (const float*)d_in[10];
    const float* g3  = (const float*)d_in[11];
    const float* be3 = (const float*)d_in[12];
    const float* Wm  = (const float*)d_in[13];
    const float* bm  = (const float*)d_in[14];
    unsigned short* ws = (unsigned short*)d_ws;
    float* out = (float*)d_out;

    conv_w_kernel<<<(WS_ELEMS + 255) / 256, 256, 0, stream>>>(W1, b1, W2, W3, Wm, ws);
    fused_mlp<<<NBLK, 256, 0, stream>>>(x, g1, be1, b2, g2, be2,
                                        b3, g3, be3, bm, ws, out);
}